// Round 18
// baseline (348.186 us; speedup 1.0000x reference)
//
#include <hip/hip_runtime.h>
#include <cstdint>

#define B_ 512
#define N_ 150
#define NT 640
#define C1f 144.26950408889634f    // log2(e)/eps, eps=0.01
#define LN2f 0.69314718055994531f
#define SIGMAf 1.0e-4f
#define INV_N (1.0f/150.0f)

// raw hardware transcendentals (1-ULP v_exp_f32 / v_log_f32)
#define EXP2R(x) __builtin_amdgcn_exp2f(x)
#define LOG2R(x) __builtin_amdgcn_logf(x)

// DPP quad-perm reduces (VALU pipe): xor1 = 0xB1, xor2 = 0x4E
#define DPPF(v, c) __int_as_float(__builtin_amdgcn_update_dpp( \
    __float_as_int(v), __float_as_int(v), (c), 0xF, 0xF, false))
#define RED4_ADD(v)  { v = v + DPPF(v, 0xB1); v = v + DPPF(v, 0x4E); }

#define REP10(X) X(0) X(1) X(2) X(3) X(4) X(5) X(6) X(7) X(8) X(9)

// Threefry-2x32, 20 rounds, exactly as JAX's threefry2x32 lowering.
__host__ __device__ __forceinline__ void tf2x32(uint32_t k0, uint32_t k1,
                                                uint32_t x0, uint32_t x1,
                                                uint32_t& o0, uint32_t& o1) {
  uint32_t ks2 = k0 ^ k1 ^ 0x1BD11BDAu;
  x0 += k0; x1 += k1;
#define TFR(r) { x0 += x1; x1 = (x1 << r) | (x1 >> (32 - r)); x1 ^= x0; }
  TFR(13) TFR(15) TFR(26) TFR(6)
  x0 += k1;  x1 += ks2 + 1u;
  TFR(17) TFR(29) TFR(16) TFR(24)
  x0 += ks2; x1 += k0 + 2u;
  TFR(13) TFR(15) TFR(26) TFR(6)
  x0 += k0;  x1 += k1 + 3u;
  TFR(17) TFR(29) TFR(16) TFR(24)
  x0 += k1;  x1 += ks2 + 4u;
  TFR(13) TFR(15) TFR(26) TFR(6)
  x0 += ks2; x1 += k0 + 5u;
#undef TFR
  o0 = x0; o1 = x1;
}

__device__ __forceinline__ uint32_t jax_bits(uint32_t k0, uint32_t k1, uint32_t p) {
  uint32_t a, b; tf2x32(k0, k1, 0u, p, a, b);   // partitionable: counter (0, p)
  return a ^ b;
}

// ==== Fused kernel: Sinkhorn + sampler + loss. R17 base; finalize sections
// spread over ALL 640 threads (was 160) to cut the latency-exposed
// inter-barrier critical path ~4x. ====
__global__ __launch_bounds__(NT, 5) void cfm_fused_kernel(
    const float* __restrict__ x1g, const float* __restrict__ maskg,
    const float* __restrict__ tg, const float* __restrict__ x0g,
    const float* __restrict__ epsg,
    const float* __restrict__ W1, const float* __restrict__ b1,
    const float* __restrict__ W2, const float* __restrict__ b2,
    float* __restrict__ partials,
    uint32_t kj0, uint32_t kj1, uint32_t k1r0, uint32_t k1r1,
    uint32_t k2r0, uint32_t k2r1)
{
  __shared__ float x1L[480], x0L[480];
  __shared__ __align__(16) float colp[16 * 164];   // [rg][164] col partials
  __shared__ __align__(16) float rowqT[10 * 162];  // [cgq][162] row partials
  __shared__ __align__(16) float vhat[160];        // v
  __shared__ __align__(16) float uhatP[16 * 12];   // u, padded rows of 12
  __shared__ float red[16];
  // sampler state
  __shared__ float psiS[152], mskS[152];
  __shared__ float yu[150 * 9];
  __shared__ float aP[2 * 160 * 3];
  __shared__ float lossS[160];
  __shared__ int   iselS[152];
  float4* colp4 = (float4*)colp;    // row stride 41
  float4* vhat4 = (float4*)vhat;

  const int b    = blockIdx.x;
  const int tid  = threadIdx.x;
  const int lane = tid & 63;
  const int wid  = tid >> 6;
  const int rg   = tid / 40;        // 0..15
  const int cg   = tid - rg * 40;   // 0..39
  const int q    = tid & 3;         // == cg&3 (40 % 4 == 0)
  const int cgq  = cg >> 2;         // 0..9
  const int rbase = rg * 10;
  const int cbase = cg * 4;
  const int rc   = tid >> 2;        // 0..159: finalize col / row owned by quad
  const int uoff = (rc / 10) * 12 + (rc % 10);   // uhatP slot for row rc

  if (tid < 480) {
    x1L[tid] = (tid < 450) ? x1g[b * 450 + tid] : 0.f;
    x0L[tid] = (tid < 450) ? x0g[b * 450 + tid] : 0.f;
  }
  if (tid < 192) uhatP[tid] = 1.0f;       // u0 = 1 (f = 0); pads harmless
  __syncthreads();

  // ---- distances into named tile regs, track block max ----
  float4 kt0, kt1, kt2, kt3, kt4, kt5, kt6, kt7, kt8, kt9;
  float lmax = 0.f;
  {
    const float c0 = x1L[cbase * 3 + 0], c1 = x1L[cbase * 3 + 1], c2 = x1L[cbase * 3 + 2];
    const float d0 = x1L[cbase * 3 + 3], d1 = x1L[cbase * 3 + 4], d2 = x1L[cbase * 3 + 5];
    const float e0 = x1L[cbase * 3 + 6], e1 = x1L[cbase * 3 + 7], e2 = x1L[cbase * 3 + 8];
    const float f0 = x1L[cbase * 3 + 9], f1 = x1L[cbase * 3 + 10], f2 = x1L[cbase * 3 + 11];
#define DIST(r) { \
    const int row = rbase + r; \
    const float rx = x0L[row * 3 + 0], ry = x0L[row * 3 + 1], rz = x0L[row * 3 + 2]; \
    float dx, dy, dz, d; \
    dx = rx - c0; dy = ry - c1; dz = rz - c2; \
    d = fmaf(dz, dz, fmaf(dy, dy, dx * dx)); \
    kt##r.x = (row < N_ && cbase + 0 < N_) ? d : 0.f; \
    dx = rx - d0; dy = ry - d1; dz = rz - d2; \
    d = fmaf(dz, dz, fmaf(dy, dy, dx * dx)); \
    kt##r.y = (row < N_ && cbase + 1 < N_) ? d : 0.f; \
    dx = rx - e0; dy = ry - e1; dz = rz - e2; \
    d = fmaf(dz, dz, fmaf(dy, dy, dx * dx)); \
    kt##r.z = (row < N_ && cbase + 2 < N_) ? d : 0.f; \
    dx = rx - f0; dy = ry - f1; dz = rz - f2; \
    d = fmaf(dz, dz, fmaf(dy, dy, dx * dx)); \
    kt##r.w = (row < N_ && cbase + 3 < N_) ? d : 0.f; \
    lmax = fmaxf(lmax, fmaxf(fmaxf(kt##r.x, kt##r.y), fmaxf(kt##r.z, kt##r.w))); }
    REP10(DIST)
#undef DIST
  }
  #pragma unroll
  for (int off = 1; off < 64; off <<= 1) lmax = fmaxf(lmax, __shfl_xor(lmax, off));
  if (lane == 0) red[wid] = lmax;
  __syncthreads();
  if (tid == 0) {
    float m = red[0];
    #pragma unroll
    for (int w = 1; w < 10; ++w) m = fmaxf(m, red[w]);
    red[15] = -C1f / m;
  }
  __syncthreads();
  const float nsc = red[15];

  // ---- K = exp2(nsc * D); pads -> 0 ----
#define TOK(r) { \
    const int row = rbase + r; \
    kt##r.x = (row < N_ && cbase + 0 < N_) ? EXP2R(nsc * kt##r.x) : 0.f; \
    kt##r.y = (row < N_ && cbase + 1 < N_) ? EXP2R(nsc * kt##r.y) : 0.f; \
    kt##r.z = (row < N_ && cbase + 2 < N_) ? EXP2R(nsc * kt##r.z) : 0.f; \
    kt##r.w = (row < N_ && cbase + 3 < N_) ? EXP2R(nsc * kt##r.w) : 0.f; }
  REP10(TOK)
#undef TOK

  // ---- 100 iterations; K read-only, only u/v updated ----
  for (int it = 0; it < 100; ++it) {
    // phase A: col partials of K^T u; u loaded as b128+b128+b64 (padded rows)
    {
      const float4 ua = *(const float4*)&uhatP[rg * 12];
      const float4 ub = *(const float4*)&uhatP[rg * 12 + 4];
      const float2 uc = *(const float2*)&uhatP[rg * 12 + 8];
      float4 p4 = make_float4(0.f, 0.f, 0.f, 0.f);
#define COLA(k, uu) { \
      p4.x = fmaf(kt##k.x, uu, p4.x); \
      p4.y = fmaf(kt##k.y, uu, p4.y); \
      p4.z = fmaf(kt##k.z, uu, p4.z); \
      p4.w = fmaf(kt##k.w, uu, p4.w); }
      COLA(0, ua.x) COLA(1, ua.y) COLA(2, ua.z) COLA(3, ua.w)
      COLA(4, ub.x) COLA(5, ub.y) COLA(6, ub.z) COLA(7, ub.w)
      COLA(8, uc.x) COLA(9, uc.y)
#undef COLA
      colp4[rg * 41 + cg] = p4;
    }
    __syncthreads();
    // finalize colsum -> vhat: SPREAD over all 640 threads (4 partials + DPP)
    {
      float s = colp[(4 * q + 0) * 164 + rc] + colp[(4 * q + 1) * 164 + rc]
              + colp[(4 * q + 2) * 164 + rc] + colp[(4 * q + 3) * 164 + rc];
      RED4_ADD(s)
      if (q == 0) vhat[rc] = __builtin_amdgcn_rcpf(fmaxf(s, 1e-37f)) * INV_N;
    }
    __syncthreads();
    // phase B: row partials of K v; quad reduce; 5x float2 stores (transposed)
    {
      const float4 vv = vhat4[cg];
#define ROWB(k) \
      float rp##k = kt##k.x * vv.x; \
      rp##k = fmaf(kt##k.y, vv.y, rp##k); \
      rp##k = fmaf(kt##k.z, vv.z, rp##k); \
      rp##k = fmaf(kt##k.w, vv.w, rp##k); \
      RED4_ADD(rp##k)
      REP10(ROWB)
#undef ROWB
      if (q == 0) {
        const int rb2 = cgq * 162 + rbase;
        *(float2*)&rowqT[rb2 + 0] = make_float2(rp0, rp1);
        *(float2*)&rowqT[rb2 + 2] = make_float2(rp2, rp3);
        *(float2*)&rowqT[rb2 + 4] = make_float2(rp4, rp5);
        *(float2*)&rowqT[rb2 + 6] = make_float2(rp6, rp7);
        *(float2*)&rowqT[rb2 + 8] = make_float2(rp8, rp9);
      }
    }
    __syncthreads();
    // finalize rowsum -> uhat: SPREAD over all 640 threads (2-3 partials + DPP)
    {
      float s = rowqT[q * 162 + rc] + rowqT[(q + 4) * 162 + rc];
      if (q < 2) s += rowqT[(q + 8) * 162 + rc];
      RED4_ADD(s)
      if (q == 0) uhatP[uoff] = __builtin_amdgcn_rcpf(fmaxf(s, 1e-37f)) * INV_N;
    }
    __syncthreads();
  }

  // ================= sampler (fused; psi stays in LDS) ======================
  if (tid < N_) {
    psiS[tid] = LOG2R(vhat[tid]);       // psi in log2 units
    mskS[tid] = maskg[b * 150 + tid];
    const uint32_t p = (uint32_t)(b * N_ + tid);
    const uint32_t hb = jax_bits(k1r0, k1r1, p);
    const uint32_t lb = jax_bits(k2r0, k2r1, p);
    iselS[tid] = (int)(((hb % 150u) * 46u + (lb % 150u)) % 150u);
  }
  const float tb = tg[b];
  __syncthreads();

  // ---- S1: gumbel argmax per sample (wave per n), store y/u/mot ----
  for (int n = wid; n < N_; n += 10) {
    const uint32_t p = (uint32_t)(b * N_ + n);
    const int isel = iselS[n];
    const float xi0 = x0L[isel * 3 + 0], xi1 = x0L[isel * 3 + 1], xi2 = x0L[isel * 3 + 2];

    float best = -1e30f; int bestk = 0x7fffffff;
    #pragma unroll
    for (int c2 = 0; c2 < 3; ++c2) {
      const int k = lane + 64 * c2;
      if (k < N_) {
        const uint32_t bits = jax_bits(kj0, kj1, p * 150u + (uint32_t)k);
        float u = __uint_as_float((bits >> 9) | 0x3F800000u) - 1.0f;
        u = fmaxf(u, 1.17549435e-38f);
        const float nlu = -LN2f * LOG2R(u);
        const float g = -LN2f * LOG2R(nlu);
        const float dx = xi0 - x1L[k * 3 + 0];
        const float dy = xi1 - x1L[k * 3 + 1];
        const float dz = xi2 - x1L[k * 3 + 2];
        const float d2 = fmaf(dz, dz, fmaf(dy, dy, dx * dx));
        const float val = fmaf(psiS[k] + nsc * d2, LN2f, g);  // phi_i const over k
        if (val > best || (val == best && k < bestk)) { best = val; bestk = k; }
      }
    }
    #pragma unroll
    for (int off = 1; off < 64; off <<= 1) {
      const float ov = __shfl_xor(best, off);
      const int   ok = __shfl_xor(bestk, off);
      if (ov > best || (ov == best && ok < bestk)) { best = ov; bestk = ok; }
    }
    if (lane == 0) {
      const int j = bestk;
      const float mot = mskS[j];
      const float q0 = x1L[j * 3 + 0], q1 = x1L[j * 3 + 1], q2 = x1L[j * 3 + 2];
      const float omt = 1.f - tb;
      yu[n * 9 + 0] = xi0 * tb + q0 * omt + SIGMAf * epsg[b * 450 + n * 3 + 0];
      yu[n * 9 + 1] = xi1 * tb + q1 * omt + SIGMAf * epsg[b * 450 + n * 3 + 1];
      yu[n * 9 + 2] = xi2 * tb + q2 * omt + SIGMAf * epsg[b * 450 + n * 3 + 2];
      yu[n * 9 + 3] = (xi0 - q0) * mot;
      yu[n * 9 + 4] = (xi1 - q1) * mot;
      yu[n * 9 + 5] = (xi2 - q2) * mot;
      yu[n * 9 + 6] = mot;
    }
  }
  __syncthreads();

  // ---- S2: MLP. wave w: half h = w/5 (uniform -> s_load hd), sample
  //      s = (w%5)*64+lane, active (w%5)<3; 256 iters over hd half ----
  {
    const int h  = wid / 5;             // 0..1, wave-uniform
    const int sw = wid - h * 5;         // 0..4
    const int s  = sw * 64 + lane;
    if (sw < 3 && s < N_) {
      const float y0 = yu[s * 9 + 0], y1 = yu[s * 9 + 1], y2 = yu[s * 9 + 2];
      float a0 = 0.f, a1 = 0.f, a2 = 0.f;
      const int h0 = h * 256;
      #pragma unroll 4
      for (int i = 0; i < 256; ++i) {
        const int hd = h0 + i;          // wave-uniform -> scalar W loads
        float z = b1[hd];
        z = fmaf(y0, W1[hd],        z);
        z = fmaf(y1, W1[512 + hd],  z);
        z = fmaf(y2, W1[1024 + hd], z);
        z = fmaf(tb, W1[1536 + hd], z);
        const float zc = fmaf(0.044715f * z, z * z, z);
        const float e2 = EXP2R(-2.3022082062161855f * zc);
        const float ge = z * __builtin_amdgcn_rcpf(1.f + e2);
        a0 = fmaf(ge, W2[hd * 3 + 0], a0);
        a1 = fmaf(ge, W2[hd * 3 + 1], a1);
        a2 = fmaf(ge, W2[hd * 3 + 2], a2);
      }
      aP[(h * 160 + s) * 3 + 0] = a0;
      aP[(h * 160 + s) * 3 + 1] = a1;
      aP[(h * 160 + s) * 3 + 2] = a2;
    }
  }
  __syncthreads();

  // ---- combine halves, finish loss per sample ----
  if (tid < N_) {
    const float a0 = aP[tid * 3 + 0] + aP[(160 + tid) * 3 + 0];
    const float a1 = aP[tid * 3 + 1] + aP[(160 + tid) * 3 + 1];
    const float a2 = aP[tid * 3 + 2] + aP[(160 + tid) * 3 + 2];
    const float mot = yu[tid * 9 + 6];
    const float v0 = (a0 + b2[0]) * mot;
    const float v1 = (a1 + b2[1]) * mot;
    const float v2 = (a2 + b2[2]) * mot;
    const float d0 = v0 - yu[tid * 9 + 3];
    const float d1 = v1 - yu[tid * 9 + 4];
    const float d2 = v2 - yu[tid * 9 + 5];
    lossS[tid] = fmaf(d2, d2, fmaf(d1, d1, d0 * d0));
  }
  __syncthreads();

  // ---- block loss reduce: wave 0 over 150 entries ----
  if (wid == 0) {
    float s = 0.f;
    #pragma unroll
    for (int k = 0; k < 3; ++k) {
      const int idx = lane + 64 * k;
      if (idx < N_) s += lossS[idx];
    }
    #pragma unroll
    for (int off = 1; off < 64; off <<= 1) s += __shfl_xor(s, off);
    if (lane == 0) partials[b] = s;
  }
}

__global__ void cfm_reduce_kernel(const float* __restrict__ partials,
                                  float* __restrict__ out) {
  const int tid = threadIdx.x;   // 64 threads
  float s = 0.f;
  #pragma unroll
  for (int q = 0; q < 8; ++q) s += partials[tid + 64 * q];
  #pragma unroll
  for (int off = 1; off < 64; off <<= 1) s += __shfl_xor(s, off);
  if (tid == 0) out[0] = s * (1.0f / 230400.0f);
}

extern "C" void kernel_launch(void* const* d_in, const int* in_sizes, int n_in,
                              void* d_out, int out_size, void* d_ws, size_t ws_size,
                              hipStream_t stream) {
  (void)in_sizes; (void)n_in; (void)out_size; (void)ws_size;
  const float* x    = (const float*)d_in[0];
  const float* mask = (const float*)d_in[1];
  const float* t    = (const float*)d_in[2];
  const float* x0n  = (const float*)d_in[3];
  const float* epsn = (const float*)d_in[4];
  const float* W1   = (const float*)d_in[5];
  const float* b1   = (const float*)d_in[6];
  const float* W2   = (const float*)d_in[7];
  const float* b2   = (const float*)d_in[8];
  float* out = (float*)d_out;
  float* partials = (float*)d_ws;              // 512 floats

  uint32_t ki0, ki1, kj0, kj1, k1r0, k1r1, k2r0, k2r1;
  tf2x32(0u, 42u, 0u, 0u, ki0, ki1);
  tf2x32(0u, 42u, 0u, 1u, kj0, kj1);
  tf2x32(ki0, ki1, 0u, 0u, k1r0, k1r1);
  tf2x32(ki0, ki1, 0u, 1u, k2r0, k2r1);

  cfm_fused_kernel<<<B_, NT, 0, stream>>>(x, mask, t, x0n, epsn, W1, b1, W2, b2,
                                          partials,
                                          kj0, kj1, k1r0, k1r1, k2r0, k2r1);
  cfm_reduce_kernel<<<1, 64, 0, stream>>>(partials, out);
}

// Round 19
// 250.432 us; speedup vs baseline: 1.3903x; 1.3903x over previous
//
#include <hip/hip_runtime.h>
#include <cstdint>

#define B_ 512
#define N_ 150
#define NT 640
#define C1f 144.26950408889634f    // log2(e)/eps, eps=0.01
#define LN2f 0.69314718055994531f
#define SIGMAf 1.0e-4f
#define INV_N (1.0f/150.0f)

// raw hardware transcendentals (1-ULP v_exp_f32 / v_log_f32)
#define EXP2R(x) __builtin_amdgcn_exp2f(x)
#define LOG2R(x) __builtin_amdgcn_logf(x)

// DPP quad-perm reduces (VALU pipe): xor1 = 0xB1, xor2 = 0x4E
#define DPPF(v, c) __int_as_float(__builtin_amdgcn_update_dpp( \
    __float_as_int(v), __float_as_int(v), (c), 0xF, 0xF, false))
#define RED4_ADD(v)  { v = v + DPPF(v, 0xB1); v = v + DPPF(v, 0x4E); }

#define REP10(X) X(0) X(1) X(2) X(3) X(4) X(5) X(6) X(7) X(8) X(9)

// Threefry-2x32, 20 rounds, exactly as JAX's threefry2x32 lowering.
__host__ __device__ __forceinline__ void tf2x32(uint32_t k0, uint32_t k1,
                                                uint32_t x0, uint32_t x1,
                                                uint32_t& o0, uint32_t& o1) {
  uint32_t ks2 = k0 ^ k1 ^ 0x1BD11BDAu;
  x0 += k0; x1 += k1;
#define TFR(r) { x0 += x1; x1 = (x1 << r) | (x1 >> (32 - r)); x1 ^= x0; }
  TFR(13) TFR(15) TFR(26) TFR(6)
  x0 += k1;  x1 += ks2 + 1u;
  TFR(17) TFR(29) TFR(16) TFR(24)
  x0 += ks2; x1 += k0 + 2u;
  TFR(13) TFR(15) TFR(26) TFR(6)
  x0 += k0;  x1 += k1 + 3u;
  TFR(17) TFR(29) TFR(16) TFR(24)
  x0 += k1;  x1 += ks2 + 4u;
  TFR(13) TFR(15) TFR(26) TFR(6)
  x0 += ks2; x1 += k0 + 5u;
#undef TFR
  o0 = x0; o1 = x1;
}

__device__ __forceinline__ uint32_t jax_bits(uint32_t k0, uint32_t k1, uint32_t p) {
  uint32_t a, b; tf2x32(k0, k1, 0u, p, a, b);   // partitionable: counter (0, p)
  return a ^ b;
}

// ==== Fused kernel: Sinkhorn (R13 loop) + sampler + loss (R16, best: 250us) ==
__global__ __launch_bounds__(NT, 5) void cfm_fused_kernel(
    const float* __restrict__ x1g, const float* __restrict__ maskg,
    const float* __restrict__ tg, const float* __restrict__ x0g,
    const float* __restrict__ epsg,
    const float* __restrict__ W1, const float* __restrict__ b1,
    const float* __restrict__ W2, const float* __restrict__ b2,
    float* __restrict__ partials,
    uint32_t kj0, uint32_t kj1, uint32_t k1r0, uint32_t k1r1,
    uint32_t k2r0, uint32_t k2r1)
{
  __shared__ float x1L[480], x0L[480];
  __shared__ __align__(16) float colp[16 * 164];   // [rg][164] col partials
  __shared__ __align__(16) float rowqT[10 * 162];  // [cgq][162] row partials
  __shared__ __align__(16) float vhat[160];        // v
  __shared__ __align__(16) float uhatP[16 * 12];   // u, padded rows of 12
  __shared__ float red[16];
  // sampler state
  __shared__ float psiS[152], mskS[152];
  __shared__ float yu[150 * 9];
  __shared__ float aP[2 * 160 * 3];
  __shared__ float lossS[160];
  __shared__ int   iselS[152];
  float4* colp4 = (float4*)colp;    // row stride 41
  float4* vhat4 = (float4*)vhat;

  const int b    = blockIdx.x;
  const int tid  = threadIdx.x;
  const int lane = tid & 63;
  const int wid  = tid >> 6;
  const int rg   = tid / 40;        // 0..15
  const int cg   = tid - rg * 40;   // 0..39
  const int q    = tid & 3;         // == cg&3 (40 % 4 == 0)
  const int cgq  = cg >> 2;         // 0..9
  const int rbase = rg * 10;
  const int cbase = cg * 4;

  if (tid < 480) {
    x1L[tid] = (tid < 450) ? x1g[b * 450 + tid] : 0.f;
    x0L[tid] = (tid < 450) ? x0g[b * 450 + tid] : 0.f;
  }
  if (tid < 192) uhatP[tid] = 1.0f;       // u0 = 1 (f = 0); pads harmless
  __syncthreads();

  // ---- distances into named tile regs, track block max ----
  float4 kt0, kt1, kt2, kt3, kt4, kt5, kt6, kt7, kt8, kt9;
  float lmax = 0.f;
  {
    const float c0 = x1L[cbase * 3 + 0], c1 = x1L[cbase * 3 + 1], c2 = x1L[cbase * 3 + 2];
    const float d0 = x1L[cbase * 3 + 3], d1 = x1L[cbase * 3 + 4], d2 = x1L[cbase * 3 + 5];
    const float e0 = x1L[cbase * 3 + 6], e1 = x1L[cbase * 3 + 7], e2 = x1L[cbase * 3 + 8];
    const float f0 = x1L[cbase * 3 + 9], f1 = x1L[cbase * 3 + 10], f2 = x1L[cbase * 3 + 11];
#define DIST(r) { \
    const int row = rbase + r; \
    const float rx = x0L[row * 3 + 0], ry = x0L[row * 3 + 1], rz = x0L[row * 3 + 2]; \
    float dx, dy, dz, d; \
    dx = rx - c0; dy = ry - c1; dz = rz - c2; \
    d = fmaf(dz, dz, fmaf(dy, dy, dx * dx)); \
    kt##r.x = (row < N_ && cbase + 0 < N_) ? d : 0.f; \
    dx = rx - d0; dy = ry - d1; dz = rz - d2; \
    d = fmaf(dz, dz, fmaf(dy, dy, dx * dx)); \
    kt##r.y = (row < N_ && cbase + 1 < N_) ? d : 0.f; \
    dx = rx - e0; dy = ry - e1; dz = rz - e2; \
    d = fmaf(dz, dz, fmaf(dy, dy, dx * dx)); \
    kt##r.z = (row < N_ && cbase + 2 < N_) ? d : 0.f; \
    dx = rx - f0; dy = ry - f1; dz = rz - f2; \
    d = fmaf(dz, dz, fmaf(dy, dy, dx * dx)); \
    kt##r.w = (row < N_ && cbase + 3 < N_) ? d : 0.f; \
    lmax = fmaxf(lmax, fmaxf(fmaxf(kt##r.x, kt##r.y), fmaxf(kt##r.z, kt##r.w))); }
    REP10(DIST)
#undef DIST
  }
  #pragma unroll
  for (int off = 1; off < 64; off <<= 1) lmax = fmaxf(lmax, __shfl_xor(lmax, off));
  if (lane == 0) red[wid] = lmax;
  __syncthreads();
  if (tid == 0) {
    float m = red[0];
    #pragma unroll
    for (int w = 1; w < 10; ++w) m = fmaxf(m, red[w]);
    red[15] = -C1f / m;
  }
  __syncthreads();
  const float nsc = red[15];

  // ---- K = exp2(nsc * D); pads -> 0 ----
#define TOK(r) { \
    const int row = rbase + r; \
    kt##r.x = (row < N_ && cbase + 0 < N_) ? EXP2R(nsc * kt##r.x) : 0.f; \
    kt##r.y = (row < N_ && cbase + 1 < N_) ? EXP2R(nsc * kt##r.y) : 0.f; \
    kt##r.z = (row < N_ && cbase + 2 < N_) ? EXP2R(nsc * kt##r.z) : 0.f; \
    kt##r.w = (row < N_ && cbase + 3 < N_) ? EXP2R(nsc * kt##r.w) : 0.f; }
  REP10(TOK)
#undef TOK

  // ---- 100 iterations; K read-only, only u/v updated (R13, unchanged) ----
  for (int it = 0; it < 100; ++it) {
    {
      const float4 ua = *(const float4*)&uhatP[rg * 12];
      const float4 ub = *(const float4*)&uhatP[rg * 12 + 4];
      const float2 uc = *(const float2*)&uhatP[rg * 12 + 8];
      float4 p4 = make_float4(0.f, 0.f, 0.f, 0.f);
#define COLA(k, uu) { \
      p4.x = fmaf(kt##k.x, uu, p4.x); \
      p4.y = fmaf(kt##k.y, uu, p4.y); \
      p4.z = fmaf(kt##k.z, uu, p4.z); \
      p4.w = fmaf(kt##k.w, uu, p4.w); }
      COLA(0, ua.x) COLA(1, ua.y) COLA(2, ua.z) COLA(3, ua.w)
      COLA(4, ub.x) COLA(5, ub.y) COLA(6, ub.z) COLA(7, ub.w)
      COLA(8, uc.x) COLA(9, uc.y)
#undef COLA
      colp4[rg * 41 + cg] = p4;
    }
    __syncthreads();
    if (tid < 160) {
      float s = 0.f;
      #pragma unroll
      for (int k = 0; k < 16; ++k) s += colp[k * 164 + tid];
      vhat[tid] = __builtin_amdgcn_rcpf(fmaxf(s, 1e-37f)) * INV_N;
    }
    __syncthreads();
    {
      const float4 vv = vhat4[cg];
#define ROWB(k) \
      float rp##k = kt##k.x * vv.x; \
      rp##k = fmaf(kt##k.y, vv.y, rp##k); \
      rp##k = fmaf(kt##k.z, vv.z, rp##k); \
      rp##k = fmaf(kt##k.w, vv.w, rp##k); \
      RED4_ADD(rp##k)
      REP10(ROWB)
#undef ROWB
      if (q == 0) {
        const int rb2 = cgq * 162 + rbase;
        *(float2*)&rowqT[rb2 + 0] = make_float2(rp0, rp1);
        *(float2*)&rowqT[rb2 + 2] = make_float2(rp2, rp3);
        *(float2*)&rowqT[rb2 + 4] = make_float2(rp4, rp5);
        *(float2*)&rowqT[rb2 + 6] = make_float2(rp6, rp7);
        *(float2*)&rowqT[rb2 + 8] = make_float2(rp8, rp9);
      }
    }
    __syncthreads();
    if (tid < 160) {
      float s = 0.f;
      #pragma unroll
      for (int u = 0; u < 10; ++u) s += rowqT[u * 162 + tid];
      const float uh = __builtin_amdgcn_rcpf(fmaxf(s, 1e-37f)) * INV_N;
      const int g = tid / 10;
      uhatP[g * 12 + (tid - g * 10)] = uh;
    }
    __syncthreads();
  }

  // ================= sampler (fused; psi stays in LDS) ======================
  if (tid < N_) {
    psiS[tid] = LOG2R(vhat[tid]);       // psi in log2 units
    mskS[tid] = maskg[b * 150 + tid];
    const uint32_t p = (uint32_t)(b * N_ + tid);
    const uint32_t hb = jax_bits(k1r0, k1r1, p);
    const uint32_t lb = jax_bits(k2r0, k2r1, p);
    iselS[tid] = (int)(((hb % 150u) * 46u + (lb % 150u)) % 150u);
  }
  const float tb = tg[b];
  __syncthreads();

  // ---- S1: gumbel argmax per sample (wave per n), store y/u/mot ----
  for (int n = wid; n < N_; n += 10) {
    const uint32_t p = (uint32_t)(b * N_ + n);
    const int isel = iselS[n];
    const float xi0 = x0L[isel * 3 + 0], xi1 = x0L[isel * 3 + 1], xi2 = x0L[isel * 3 + 2];

    float best = -1e30f; int bestk = 0x7fffffff;
    #pragma unroll
    for (int c2 = 0; c2 < 3; ++c2) {
      const int k = lane + 64 * c2;
      if (k < N_) {
        const uint32_t bits = jax_bits(kj0, kj1, p * 150u + (uint32_t)k);
        float u = __uint_as_float((bits >> 9) | 0x3F800000u) - 1.0f;
        u = fmaxf(u, 1.17549435e-38f);
        const float nlu = -LN2f * LOG2R(u);
        const float g = -LN2f * LOG2R(nlu);
        const float dx = xi0 - x1L[k * 3 + 0];
        const float dy = xi1 - x1L[k * 3 + 1];
        const float dz = xi2 - x1L[k * 3 + 2];
        const float d2 = fmaf(dz, dz, fmaf(dy, dy, dx * dx));
        const float val = fmaf(psiS[k] + nsc * d2, LN2f, g);  // phi_i const over k
        if (val > best || (val == best && k < bestk)) { best = val; bestk = k; }
      }
    }
    #pragma unroll
    for (int off = 1; off < 64; off <<= 1) {
      const float ov = __shfl_xor(best, off);
      const int   ok = __shfl_xor(bestk, off);
      if (ov > best || (ov == best && ok < bestk)) { best = ov; bestk = ok; }
    }
    if (lane == 0) {
      const int j = bestk;
      const float mot = mskS[j];
      const float q0 = x1L[j * 3 + 0], q1 = x1L[j * 3 + 1], q2 = x1L[j * 3 + 2];
      const float omt = 1.f - tb;
      yu[n * 9 + 0] = xi0 * tb + q0 * omt + SIGMAf * epsg[b * 450 + n * 3 + 0];
      yu[n * 9 + 1] = xi1 * tb + q1 * omt + SIGMAf * epsg[b * 450 + n * 3 + 1];
      yu[n * 9 + 2] = xi2 * tb + q2 * omt + SIGMAf * epsg[b * 450 + n * 3 + 2];
      yu[n * 9 + 3] = (xi0 - q0) * mot;
      yu[n * 9 + 4] = (xi1 - q1) * mot;
      yu[n * 9 + 5] = (xi2 - q2) * mot;
      yu[n * 9 + 6] = mot;
    }
  }
  __syncthreads();

  // ---- S2: MLP. wave w: half h = w/5 (uniform -> s_load hd), sample
  //      s = (w%5)*64+lane, active (w%5)<3; 256 iters over hd half ----
  {
    const int h  = wid / 5;             // 0..1, wave-uniform
    const int sw = wid - h * 5;         // 0..4
    const int s  = sw * 64 + lane;
    if (sw < 3 && s < N_) {
      const float y0 = yu[s * 9 + 0], y1 = yu[s * 9 + 1], y2 = yu[s * 9 + 2];
      float a0 = 0.f, a1 = 0.f, a2 = 0.f;
      const int h0 = h * 256;
      #pragma unroll 4
      for (int i = 0; i < 256; ++i) {
        const int hd = h0 + i;          // wave-uniform -> scalar W loads
        float z = b1[hd];
        z = fmaf(y0, W1[hd],        z);
        z = fmaf(y1, W1[512 + hd],  z);
        z = fmaf(y2, W1[1024 + hd], z);
        z = fmaf(tb, W1[1536 + hd], z);
        const float zc = fmaf(0.044715f * z, z * z, z);
        const float e2 = EXP2R(-2.3022082062161855f * zc);
        const float ge = z * __builtin_amdgcn_rcpf(1.f + e2);
        a0 = fmaf(ge, W2[hd * 3 + 0], a0);
        a1 = fmaf(ge, W2[hd * 3 + 1], a1);
        a2 = fmaf(ge, W2[hd * 3 + 2], a2);
      }
      aP[(h * 160 + s) * 3 + 0] = a0;
      aP[(h * 160 + s) * 3 + 1] = a1;
      aP[(h * 160 + s) * 3 + 2] = a2;
    }
  }
  __syncthreads();

  // ---- combine halves, finish loss per sample ----
  if (tid < N_) {
    const float a0 = aP[tid * 3 + 0] + aP[(160 + tid) * 3 + 0];
    const float a1 = aP[tid * 3 + 1] + aP[(160 + tid) * 3 + 1];
    const float a2 = aP[tid * 3 + 2] + aP[(160 + tid) * 3 + 2];
    const float mot = yu[tid * 9 + 6];
    const float v0 = (a0 + b2[0]) * mot;
    const float v1 = (a1 + b2[1]) * mot;
    const float v2 = (a2 + b2[2]) * mot;
    const float d0 = v0 - yu[tid * 9 + 3];
    const float d1 = v1 - yu[tid * 9 + 4];
    const float d2 = v2 - yu[tid * 9 + 5];
    lossS[tid] = fmaf(d2, d2, fmaf(d1, d1, d0 * d0));
  }
  __syncthreads();

  // ---- block loss reduce: wave 0 over 150 entries ----
  if (wid == 0) {
    float s = 0.f;
    #pragma unroll
    for (int k = 0; k < 3; ++k) {
      const int idx = lane + 64 * k;
      if (idx < N_) s += lossS[idx];
    }
    #pragma unroll
    for (int off = 1; off < 64; off <<= 1) s += __shfl_xor(s, off);
    if (lane == 0) partials[b] = s;
  }
}

__global__ void cfm_reduce_kernel(const float* __restrict__ partials,
                                  float* __restrict__ out) {
  const int tid = threadIdx.x;   // 64 threads
  float s = 0.f;
  #pragma unroll
  for (int q = 0; q < 8; ++q) s += partials[tid + 64 * q];
  #pragma unroll
  for (int off = 1; off < 64; off <<= 1) s += __shfl_xor(s, off);
  if (tid == 0) out[0] = s * (1.0f / 230400.0f);
}

extern "C" void kernel_launch(void* const* d_in, const int* in_sizes, int n_in,
                              void* d_out, int out_size, void* d_ws, size_t ws_size,
                              hipStream_t stream) {
  (void)in_sizes; (void)n_in; (void)out_size; (void)ws_size;
  const float* x    = (const float*)d_in[0];
  const float* mask = (const float*)d_in[1];
  const float* t    = (const float*)d_in[2];
  const float* x0n  = (const float*)d_in[3];
  const float* epsn = (const float*)d_in[4];
  const float* W1   = (const float*)d_in[5];
  const float* b1   = (const float*)d_in[6];
  const float* W2   = (const float*)d_in[7];
  const float* b2   = (const float*)d_in[8];
  float* out = (float*)d_out;
  float* partials = (float*)d_ws;              // 512 floats

  uint32_t ki0, ki1, kj0, kj1, k1r0, k1r1, k2r0, k2r1;
  tf2x32(0u, 42u, 0u, 0u, ki0, ki1);
  tf2x32(0u, 42u, 0u, 1u, kj0, kj1);
  tf2x32(ki0, ki1, 0u, 0u, k1r0, k1r1);
  tf2x32(ki0, ki1, 0u, 1u, k2r0, k2r1);

  cfm_fused_kernel<<<B_, NT, 0, stream>>>(x, mask, t, x0n, epsn, W1, b1, W2, b2,
                                          partials,
                                          kj0, kj1, k1r0, k1r1, k2r0, k2r1);
  cfm_reduce_kernel<<<1, 64, 0, stream>>>(partials, out);
}